// Round 6
// baseline (348.019 us; speedup 1.0000x reference)
//
#include <hip/hip_runtime.h>
#include <hip/hip_bf16.h>

// MC3DAD kNN(k=5) covariance-trace curvature. B=8, N=4096, f32.
// Round 6: strip-pruned exact kNN with the ENTIRE sorted batch in LDS.
//   K1 (r5-proven): per batch, counting-sort points into 128 x-strips.
//   K2: 256 blocks x 128 threads; block stages the whole sorted batch
//       (float4 + orig-idx u16 + strip table) into LDS once, then each of
//       the 2 waves serves 64 sorted-consecutive queries (query-per-lane).
//       Inner loop: broadcast ds_read of one candidate, fmaf filter vs
//       inflated lagged tau, always-write LDS append; drains recompute the
//       exact numpy tree and insert packed u64 keys
//       (bits(max(dd,0))<<32 | orig_idx<<16 | sorted_pos) via strict-<
//       min/max network (scan-order independent; orig_idx unique => the
//       sorted_pos payload never affects ordering). Strip walk = r5's
//       clamp-safe edge-bound outward expansion with tightening tau
//       (+1e-3 slack). No syncthreads / no global memory after staging.
//   K3 (r1-proven): curvature normalization in-place on d_out.

typedef unsigned long long ull;
typedef unsigned short u16;
typedef unsigned int u32;

constexpr int   N_PTS  = 4096;
constexpr int   BATCH  = 8;
constexpr int   KNN    = 5;
constexpr int   NSTRIP = 128;
constexpr float XMIN   = -5.0f;
constexpr float STRIPW = 0.078125f;    // 10/128, exact in fp32
constexpr float INVW   = 12.8f;
constexpr int   NTHR   = 128;          // 2 waves, 128 queries per block
constexpr int   KSLOT  = 16;           // per-thread append slots
constexpr int   TRIG   = 12;           // drain trigger (checked every <=4)
constexpr float FILT_MARGIN = 1e-4f;   // fast-filter false-reject slack
constexpr float STRIP_SLACK = 1e-3f;   // strip-skip slack (>> fp32 expansion err)

__device__ __forceinline__ ull umin64(ull a, ull b) { return a < b ? a : b; }
__device__ __forceinline__ ull umax64(ull a, ull b) { return a < b ? b : a; }

// ---------------- K1: counting sort into x-strips (r5 verbatim) ----------------
__global__ __launch_bounds__(256)
void build_kernel(const float* __restrict__ pcd, float4* __restrict__ spts,
                  u16* __restrict__ sidx, u32* __restrict__ table)
{
    __shared__ u32 hist[NSTRIP];
    __shared__ u32 cur[NSTRIP];
    const int b = blockIdx.x;
    const int t = threadIdx.x;
    const float* __restrict__ batch = pcd + (size_t)b * N_PTS * 3;

    if (t < NSTRIP) hist[t] = 0;
    __syncthreads();

    float px[16], py[16], pz[16]; int ps[16];
    #pragma unroll
    for (int i = 0; i < 16; ++i) {
        const int p = t + i * 256;
        const float x = batch[p * 3 + 0];
        const float y = batch[p * 3 + 1];
        const float z = batch[p * 3 + 2];
        px[i] = x; py[i] = y; pz[i] = z;
        int s = (int)floorf((x - XMIN) * INVW);
        s = s < 0 ? 0 : (s > NSTRIP - 1 ? NSTRIP - 1 : s);
        ps[i] = s;
        atomicAdd(&hist[s], 1u);
    }
    __syncthreads();
    for (int off = 1; off < NSTRIP; off <<= 1) {
        u32 v = 0;
        if (t < NSTRIP && t >= off) v = hist[t - off];
        __syncthreads();
        if (t < NSTRIP) hist[t] += v;
        __syncthreads();
    }
    if (t < NSTRIP) {
        const u32 st = (t == 0) ? 0u : hist[t - 1];
        cur[t] = st;
        table[(size_t)b * 130 + t] = st;
    }
    if (t == 0) table[(size_t)b * 130 + NSTRIP] = hist[NSTRIP - 1];  // 4096
    __syncthreads();

    float4* __restrict__ bp = spts + (size_t)b * N_PTS;
    u16*    __restrict__ bi = sidx + (size_t)b * N_PTS;
    #pragma unroll
    for (int i = 0; i < 16; ++i) {
        const int p = t + i * 256;
        const u32 pos = atomicAdd(&cur[ps[i]], 1u);
        const float x = px[i], y = py[i], z = pz[i];
        const float w = __fadd_rn(__fadd_rn(__fmul_rn(x, x), __fmul_rn(y, y)),
                                  __fmul_rn(z, z));            // exact |p|^2 tree
        bp[pos] = make_float4(x, y, z, w);
        bi[pos] = (u16)p;
    }
}

// ---------------- K2: all-LDS strip-pruned exact kNN + trace ----------------
__global__ __launch_bounds__(NTHR)
void knn_kernel(const float4* __restrict__ spts, const u16* __restrict__ sidx,
                const u32* __restrict__ table, float* __restrict__ trace_out)
{
    __shared__ float4 pts[N_PTS];          // 64 KB sorted {x,y,z,|p|^2}
    __shared__ u16    oidx[N_PTS];         // 8 KB orig indices
    __shared__ u32    tbl[NSTRIP + 1];     // strip offsets
    __shared__ u16    buf[KSLOT * NTHR];   // 4 KB append buffer

    const int b = blockIdx.y;
    const int t = threadIdx.x;
    const int lane = t & 63;

    const float4* __restrict__ bp = spts  + (size_t)b * N_PTS;
    const u16*    __restrict__ bi = sidx  + (size_t)b * N_PTS;
    const u32*    __restrict__ bt = table + (size_t)b * 130;

    // ---- stage whole sorted batch ----
    #pragma unroll
    for (int i = 0; i < N_PTS / NTHR; ++i) pts[t + i * NTHR] = bp[t + i * NTHR];
    #pragma unroll
    for (int i = 0; i < N_PTS / NTHR; ++i) oidx[t + i * NTHR] = bi[t + i * NTHR];
    if (t < NSTRIP) tbl[t] = bt[t];
    if (t == 0)     tbl[NSTRIP] = bt[NSTRIP];
    __syncthreads();

    // ---- my query (sorted position) ----
    const int qs = blockIdx.x * NTHR + t;
    const float4 q4 = pts[qs];
    const float qx = q4.x, qy = q4.y, qz = q4.z, qw = q4.w;

    // ---- seed tau: exact dd of 5 bucket-neighbors (incl. self => valid UB) ----
    float tau = 0.0f;
    {
        int w0 = qs - 2;
        w0 = w0 < 0 ? 0 : (w0 > N_PTS - 5 ? N_PTS - 5 : w0);
        #pragma unroll
        for (int i = 0; i < 5; ++i) {
            const float4 c = pts[w0 + i];
            const float dot = __fadd_rn(__fadd_rn(__fmul_rn(qx, c.x),
                                                  __fmul_rn(qy, c.y)),
                                        __fmul_rn(qz, c.z));
            const float dd  = __fsub_rn(__fadd_rn(qw, c.w), __fmul_rn(2.0f, dot));
            tau = fmaxf(tau, dd);
        }
    }
    float tauf = tau - qw + FILT_MARGIN;

    ull key[KNN];
    #pragma unroll
    for (int r = 0; r < KNN; ++r) key[r] = 0x7f800000ffffffffULL;  // (+inf, ~0)

    int cnt = 0;

    // exact-tree drain of appended candidates (all data in LDS)
    auto drain = [&]() {
        for (int j = 0; __any(j < cnt); ++j) {
            if (j < cnt) {
                const int sp = buf[j * NTHR + t];
                const float4 c = pts[sp];
                const float dot = __fadd_rn(__fadd_rn(__fmul_rn(qx, c.x),
                                                      __fmul_rn(qy, c.y)),
                                            __fmul_rn(qz, c.z));
                const float dd  = __fsub_rn(__fadd_rn(qw, c.w),
                                            __fmul_rn(2.0f, dot));
                const float ddk = fmaxf(dd, 0.0f);            // ref: max(d2,0)
                ull a = ((ull)__float_as_uint(ddk) << 32)
                      | ((u32)oidx[sp] << 16) | (u32)sp;
                #pragma unroll
                for (int p = 0; p < KNN; ++p) {               // strict-< insert
                    const ull lo = umin64(a, key[p]);
                    const ull hi = umax64(a, key[p]);
                    key[p] = lo; a = hi;
                }
            }
        }
        cnt = 0;
        tau  = fminf(tau, __uint_as_float((u32)(key[KNN - 1] >> 32)));
        tauf = tau - qw + FILT_MARGIN;
    };

    // scan sorted positions [st,en): broadcast read + fmaf filter + append
    auto scan_range = [&](int st, int en) {
        for (int j0 = st; j0 < en; j0 += 4) {
            const int je = (j0 + 4 < en) ? j0 + 4 : en;
            for (int j = j0; j < je; ++j) {
                const float4 c = pts[j];
                const float t2 = fmaf(-2.0f,
                                      fmaf(qx, c.x, fmaf(qy, c.y, qz * c.z)),
                                      c.w);
                const bool keep = t2 < tauf;
                buf[cnt * NTHR + t] = (u16)j;                 // always-write
                cnt += keep ? 1 : 0;
            }
            if (__any(cnt > TRIG)) drain();
        }
        drain();                                              // exit tight & empty
    };

    // ---- strip of my query from the table (authoritative, clamp-safe) ----
    int lo = 0, hi = NSTRIP;                                  // tbl[lo]<=qs<tbl[hi]
    while (hi - lo > 1) {
        const int mid = (lo + hi) >> 1;
        if (tbl[mid] <= (u32)qs) lo = mid; else hi = mid;
    }
    const int myS = lo;
    const int sLo = __builtin_amdgcn_readlane(myS, 0);        // sorted => min
    const int sHi = __builtin_amdgcn_readlane(myS, 63);       // sorted => max

    // ---- base strips (contiguous positions, includes self) ----
    scan_range((int)tbl[sLo], (int)tbl[sHi + 1]);

    // ---- adaptive outward expansion (r5-proven edge bounds + slack) ----
    int sR = sHi + 1, sL = sLo - 1;
    while (true) {
        const float lim = tau + STRIP_SLACK;
        bool nR = false, nL = false;
        if (sR < NSTRIP) {
            const float gap = fmaxf((XMIN + sR * STRIPW) - qx, 0.0f);
            nR = gap * gap < lim;
        }
        if (sL >= 0) {
            const float gap = fmaxf(qx - (XMIN + (sL + 1) * STRIPW), 0.0f);
            nL = gap * gap < lim;
        }
        const bool aR = __any(nR), aL = __any(nL);
        if (!aR && !aL) break;
        if (aR) { scan_range((int)tbl[sR], (int)tbl[sR + 1]); ++sR; }
        else sR = NSTRIP;                                     // tau only tightens
        if (aL) { scan_range((int)tbl[sL], (int)tbl[sL + 1]); --sL; }
        else sL = -1;
    }

    // ---- sqrt-rerank by (dist, orig_idx), centroid, covariance trace ----
    ull k2[KNN];
    #pragma unroll
    for (int r = 0; r < KNN; ++r) {
        const float dd = __uint_as_float((u32)(key[r] >> 32));
        const float dist = __fsqrt_rn(dd);                    // dd >= 0 already
        k2[r] = ((ull)__float_as_uint(dist) << 32) | (key[r] & 0xffffffffULL);
    }
    #pragma unroll
    for (int i = 0; i < KNN - 1; ++i)
        #pragma unroll
        for (int p = 0; p < KNN - 1 - i; ++p) {
            const ull lo2 = umin64(k2[p], k2[p + 1]);
            const ull hi2 = umax64(k2[p], k2[p + 1]);
            k2[p] = lo2; k2[p + 1] = hi2;
        }

    float nx[KNN], ny[KNN], nz[KNN];
    #pragma unroll
    for (int r = 0; r < KNN; ++r) {
        const int sp = (int)(k2[r] & 0xffffULL);              // sorted pos payload
        const float4 p = pts[sp];
        nx[r] = p.x; ny[r] = p.y; nz[r] = p.z;
    }
    float sx = nx[0], sy = ny[0], sz = nz[0];
    #pragma unroll
    for (int r = 1; r < KNN; ++r) {
        sx = __fadd_rn(sx, nx[r]);
        sy = __fadd_rn(sy, ny[r]);
        sz = __fadd_rn(sz, nz[r]);
    }
    const float cx = __fdiv_rn(sx, 5.0f);
    const float cy = __fdiv_rn(sy, 5.0f);
    const float cz = __fdiv_rn(sz, 5.0f);

    float sxx = 0.0f, syy = 0.0f, szz = 0.0f;
    #pragma unroll
    for (int r = 0; r < KNN; ++r) {
        const float dx = __fsub_rn(nx[r], cx);
        const float dy = __fsub_rn(ny[r], cy);
        const float dz = __fsub_rn(nz[r], cz);
        sxx = __fadd_rn(sxx, __fmul_rn(dx, dx));
        syy = __fadd_rn(syy, __fmul_rn(dy, dy));
        szz = __fadd_rn(szz, __fmul_rn(dz, dz));
    }
    const float trace = __fadd_rn(__fadd_rn(__fmul_rn(sxx, 0.25f),
                                            __fmul_rn(syy, 0.25f)),
                                  __fmul_rn(szz, 0.25f));
    trace_out[(size_t)b * N_PTS + oidx[qs]] = trace;
    (void)lane;
}

// ---------------- K3: r1-proven curvature normalize (in-place) ----------------
__global__ __launch_bounds__(256)
void curvature_kernel(float* __restrict__ io)
{
    __shared__ float red[256];
    const int b = blockIdx.x;
    const int t = threadIdx.x;
    float* __restrict__ tr = io + (size_t)b * N_PTS;

    float v[16];
    float s = 0.0f;
    #pragma unroll
    for (int i = 0; i < 16; ++i) {
        v[i] = tr[t + i * 256];
        s += v[i];
    }
    red[t] = s;
    __syncthreads();
    #pragma unroll
    for (int o = 128; o > 0; o >>= 1) {
        if (t < o) red[t] += red[t + o];
        __syncthreads();
    }
    const float denom = red[0] + 1e-8f;
    #pragma unroll
    for (int i = 0; i < 16; ++i)
        tr[t + i * 256] = v[i] / denom;
}

extern "C" void kernel_launch(void* const* d_in, const int* in_sizes, int n_in,
                              void* d_out, int out_size, void* d_ws, size_t ws_size,
                              hipStream_t stream)
{
    (void)in_sizes; (void)n_in; (void)out_size; (void)ws_size;
    const float* pcd = (const float*)d_in[0];   // [8,4096,3] f32
    float* out = (float*)d_out;                 // [8,4096] f32

    char* w = (char*)d_ws;
    float4* spts  = (float4*)w;                         // 512 KB
    u16*    sidxp = (u16*)(w + 524288);                 // 64 KB
    u32*    table = (u32*)(w + 524288 + 65536);         // 8*130*4 B

    build_kernel<<<BATCH, 256, 0, stream>>>(pcd, spts, sidxp, table);
    dim3 g2(N_PTS / NTHR, BATCH);                       // 32 x 8 = 256 blocks
    knn_kernel<<<g2, NTHR, 0, stream>>>(spts, sidxp, table, out);
    curvature_kernel<<<BATCH, 256, 0, stream>>>(out);
}

// Round 7
// 186.635 us; speedup vs baseline: 1.8647x; 1.8647x over previous
//
#include <hip/hip_runtime.h>
#include <hip/hip_bf16.h>

// MC3DAD kNN(k=5) covariance-trace curvature. B=8, N=4096, f32.
// Round 7: strip-pruned exact kNN, global-direct (L2-resident sorted batch),
// 8 lanes per query, ZERO LDS / ZERO barriers in the kNN kernel.
//   K1 (r5/r6-proven): counting-sort each batch into 128 x-strips.
//   K2: 512 blocks x 512 thr = 4096 waves (16/CU, 4/SIMD). Wave = 8
//       sorted-consecutive queries (qi=lane&7) x 8 segments (seg=lane>>3);
//       scans the wave's union strip range with stride-8 per seg lane,
//       unroll-2 global float4 loads for ILP. Fast fmaf filter vs inflated
//       lagged tau (margin 1e-4, r5/r6-proven); on __any(keep) the exact
//       numpy-tree dd is recomputed from the same registers and inserted
//       into packed u64 keys (bits(max(dd,0))<<32 | oidx<<16 | sorted_pos)
//       via strict-< min/max network (scan-order independent). tau
//       butterfly-shared across the 8 seg lanes (masks 8/16/32). Strip
//       walk = r6's clamp-safe edge-bound outward expansion (+1e-3 slack).
//       Final: butterfly key merge over seg bits, sqrt-rerank by
//       (dist, orig_idx), r1-verbatim centroid/covariance trace.
//   K3 (r1-proven): curvature normalization in-place on d_out.

typedef unsigned long long ull;
typedef unsigned short u16;
typedef unsigned int u32;

constexpr int   N_PTS  = 4096;
constexpr int   BATCH  = 8;
constexpr int   KNN    = 5;
constexpr int   NSTRIP = 128;
constexpr float XMIN   = -5.0f;
constexpr float STRIPW = 0.078125f;    // 5/64, exact in fp32
constexpr float INVW   = 12.8f;
constexpr int   NTHR   = 512;          // 8 waves, 64 queries per block
constexpr int   QPW    = 8;            // queries per wave
constexpr float FILT_MARGIN = 1e-4f;   // fast-filter false-reject slack
constexpr float STRIP_SLACK = 1e-3f;   // strip-skip slack (>> fp32 tree err)

__device__ __forceinline__ ull umin64(ull a, ull b) { return a < b ? a : b; }
__device__ __forceinline__ ull umax64(ull a, ull b) { return a < b ? b : a; }

// Merge two ascending sorted 5-lists (u64 lex keys) -> ascending bottom-5.
__device__ __forceinline__ void merge5(ull a[KNN], const ull b[KNN])
{
    const ull r0 = umin64(a[0], b[0]);
    const ull r1 = umin64(umin64(a[1], b[1]), umax64(a[0], b[0]));
    const ull r2 = umin64(umin64(a[2], b[2]),
                          umin64(umax64(a[1], b[0]), umax64(a[0], b[1])));
    const ull r3 = umin64(umin64(a[3], b[3]),
                   umin64(umax64(a[2], b[0]),
                   umin64(umax64(a[1], b[1]), umax64(a[0], b[2]))));
    const ull r4 = umin64(umin64(a[4], b[4]),
                   umin64(umin64(umax64(a[3], b[0]), umax64(a[2], b[1])),
                          umin64(umax64(a[1], b[2]), umax64(a[0], b[3]))));
    a[0] = r0; a[1] = r1; a[2] = r2; a[3] = r3; a[4] = r4;
}

// ---------------- K1: counting sort into x-strips (r5/r6 verbatim) ----------------
__global__ __launch_bounds__(256)
void build_kernel(const float* __restrict__ pcd, float4* __restrict__ spts,
                  u16* __restrict__ sidx, u32* __restrict__ table)
{
    __shared__ u32 hist[NSTRIP];
    __shared__ u32 cur[NSTRIP];
    const int b = blockIdx.x;
    const int t = threadIdx.x;
    const float* __restrict__ batch = pcd + (size_t)b * N_PTS * 3;

    if (t < NSTRIP) hist[t] = 0;
    __syncthreads();

    float px[16], py[16], pz[16]; int ps[16];
    #pragma unroll
    for (int i = 0; i < 16; ++i) {
        const int p = t + i * 256;
        const float x = batch[p * 3 + 0];
        const float y = batch[p * 3 + 1];
        const float z = batch[p * 3 + 2];
        px[i] = x; py[i] = y; pz[i] = z;
        int s = (int)floorf((x - XMIN) * INVW);
        s = s < 0 ? 0 : (s > NSTRIP - 1 ? NSTRIP - 1 : s);
        ps[i] = s;
        atomicAdd(&hist[s], 1u);
    }
    __syncthreads();
    for (int off = 1; off < NSTRIP; off <<= 1) {
        u32 v = 0;
        if (t < NSTRIP && t >= off) v = hist[t - off];
        __syncthreads();
        if (t < NSTRIP) hist[t] += v;
        __syncthreads();
    }
    if (t < NSTRIP) {
        const u32 st = (t == 0) ? 0u : hist[t - 1];
        cur[t] = st;
        table[(size_t)b * 130 + t] = st;
    }
    if (t == 0) table[(size_t)b * 130 + NSTRIP] = hist[NSTRIP - 1];  // 4096
    __syncthreads();

    float4* __restrict__ bp = spts + (size_t)b * N_PTS;
    u16*    __restrict__ bi = sidx + (size_t)b * N_PTS;
    #pragma unroll
    for (int i = 0; i < 16; ++i) {
        const int p = t + i * 256;
        const u32 pos = atomicAdd(&cur[ps[i]], 1u);
        const float x = px[i], y = py[i], z = pz[i];
        const float w = __fadd_rn(__fadd_rn(__fmul_rn(x, x), __fmul_rn(y, y)),
                                  __fmul_rn(z, z));            // exact |p|^2 tree
        bp[pos] = make_float4(x, y, z, w);
        bi[pos] = (u16)p;
    }
}

// ---------------- K2: global-direct strip-pruned exact kNN + trace ----------------
__global__ __launch_bounds__(NTHR)
void knn_kernel(const float* __restrict__ pcd, const float4* __restrict__ spts,
                const u16* __restrict__ sidx, const u32* __restrict__ table,
                float* __restrict__ trace_out)
{
    const int b    = blockIdx.y;
    const int t    = threadIdx.x;
    const int lane = t & 63;
    const int wave = t >> 6;
    const int qi   = lane & 7;             // query within wave
    const int seg  = lane >> 3;            // candidate segment 0..7

    const float4* __restrict__ bp    = spts  + (size_t)b * N_PTS;
    const u16*    __restrict__ bi    = sidx  + (size_t)b * N_PTS;
    const u32*    __restrict__ bt    = table + (size_t)b * 130;
    const float*  __restrict__ batch = pcd   + (size_t)b * N_PTS * 3;

    const int qs = blockIdx.x * (NTHR / 64 * QPW) + wave * QPW + qi;
    const float4 q4 = bp[qs];
    const float qx = q4.x, qy = q4.y, qz = q4.z, qw = q4.w;

    // ---- seed tau: exact dd of 5 bucket-neighbors (incl. self => valid UB) ----
    float tau = 0.0f;
    {
        int w0 = qs - 2;
        w0 = w0 < 0 ? 0 : (w0 > N_PTS - 5 ? N_PTS - 5 : w0);
        #pragma unroll
        for (int i = 0; i < 5; ++i) {
            const float4 c = bp[w0 + i];
            const float dot = __fadd_rn(__fadd_rn(__fmul_rn(qx, c.x),
                                                  __fmul_rn(qy, c.y)),
                                        __fmul_rn(qz, c.z));
            const float dd  = __fsub_rn(__fadd_rn(qw, c.w), __fmul_rn(2.0f, dot));
            tau = fmaxf(tau, dd);
        }
    }
    float tauf = tau - qw + FILT_MARGIN;

    ull key[KNN];
    #pragma unroll
    for (int r = 0; r < KNN; ++r) key[r] = 0x7f800000ffffffffULL;  // (+inf, ~0)

    // exact-tree insert from registers (no re-read); no-op lanes push all-ones
    auto insert_exact = [&](const float4 c, u32 oi, int ci, bool keep) {
        const float dot = __fadd_rn(__fadd_rn(__fmul_rn(qx, c.x),
                                              __fmul_rn(qy, c.y)),
                                    __fmul_rn(qz, c.z));
        const float dd  = __fsub_rn(__fadd_rn(qw, c.w), __fmul_rn(2.0f, dot));
        const float ddk = fmaxf(dd, 0.0f);                    // ref: max(d2,0)
        ull a = keep ? (((ull)__float_as_uint(ddk) << 32) | (oi << 16) | (u32)ci)
                     : 0xffffffffffffffffULL;
        #pragma unroll
        for (int p = 0; p < KNN; ++p) {                       // strict-< insert
            const ull lo = umin64(a, key[p]);
            const ull hi = umax64(a, key[p]);
            key[p] = lo; a = hi;
        }
    };

    auto share_tau = [&]() {
        tau = fminf(tau, __uint_as_float((u32)(key[KNN - 1] >> 32)));
        #pragma unroll
        for (int mask = 8; mask < 64; mask <<= 1)
            tau = fminf(tau, __shfl_xor(tau, mask));          // seg-group min
        tauf = tau - qw + FILT_MARGIN;
    };

    // scan sorted positions [st,en): stride-8 per seg lane, unroll-2 ILP
    auto scan_range = [&](int st, int en) {
        int idx = st + seg;
        while (__any(idx < en)) {
            const bool i0 = idx < en;
            const bool i1 = idx + 8 < en;
            const int  a0 = i0 ? idx : st;
            const int  a1 = i1 ? idx + 8 : st;
            const float4 c0 = bp[a0];
            const float4 c1 = bp[a1];
            const u32 o0 = bi[a0];
            const u32 o1 = bi[a1];
            const float t20 = fmaf(-2.0f,
                                   fmaf(qx, c0.x, fmaf(qy, c0.y, qz * c0.z)),
                                   c0.w);
            const float t21 = fmaf(-2.0f,
                                   fmaf(qx, c1.x, fmaf(qy, c1.y, qz * c1.z)),
                                   c1.w);
            const bool k0 = i0 && (t20 < tauf);
            const bool k1 = i1 && (t21 < tauf);
            if (__any(k0 || k1)) {
                insert_exact(c0, o0, a0, k0);
                insert_exact(c1, o1, a1, k1);
                share_tau();
            }
            idx += 16;
        }
    };

    // ---- strip of my query (same clamped formula as the build binning) ----
    int myS = (int)floorf((qx - XMIN) * INVW);
    myS = myS < 0 ? 0 : (myS > NSTRIP - 1 ? NSTRIP - 1 : myS);
    const int sLo = __builtin_amdgcn_readlane(myS, 0);        // sorted => min
    const int sHi = __builtin_amdgcn_readlane(myS, 63);       // sorted => max

    // ---- base strips (contiguous, includes self) ----
    scan_range((int)bt[sLo], (int)bt[sHi + 1]);

    // ---- adaptive outward expansion (r6-proven edge bounds + slack) ----
    int sR = sHi + 1, sL = sLo - 1;
    while (true) {
        const float lim = tau + STRIP_SLACK;
        bool nR = false, nL = false;
        if (sR < NSTRIP) {
            const float gap = fmaxf((XMIN + sR * STRIPW) - qx, 0.0f);
            nR = gap * gap < lim;
        }
        if (sL >= 0) {
            const float gap = fmaxf(qx - (XMIN + (sL + 1) * STRIPW), 0.0f);
            nL = gap * gap < lim;
        }
        const bool aR = __any(nR), aL = __any(nL);
        if (!aR && !aL) break;
        if (aR) { scan_range((int)bt[sR], (int)bt[sR + 1]); ++sR; }
        else sR = NSTRIP;                                     // tau only tightens
        if (aL) { scan_range((int)bt[sL], (int)bt[sL + 1]); --sL; }
        else sL = -1;
    }

    // ---- butterfly key merge across the 8 seg lanes ----
    #pragma unroll
    for (int mask = 8; mask < 64; mask <<= 1) {
        ull o[KNN];
        #pragma unroll
        for (int r = 0; r < KNN; ++r) o[r] = __shfl_xor(key[r], mask);
        merge5(key, o);
    }

    // ---- epilogue on seg==0 lanes: sqrt-rerank, centroid, cov trace ----
    if (seg == 0) {
        ull k2[KNN];
        #pragma unroll
        for (int r = 0; r < KNN; ++r) {
            const float dd = __uint_as_float((u32)(key[r] >> 32));
            const float dist = __fsqrt_rn(dd);                // dd >= 0 already
            k2[r] = ((ull)__float_as_uint(dist) << 32) | (key[r] & 0xffffffffULL);
        }
        #pragma unroll
        for (int i = 0; i < KNN - 1; ++i)                     // bubble by (dist,oidx)
            #pragma unroll
            for (int p = 0; p < KNN - 1 - i; ++p) {
                const ull lo2 = umin64(k2[p], k2[p + 1]);
                const ull hi2 = umax64(k2[p], k2[p + 1]);
                k2[p] = lo2; k2[p + 1] = hi2;
            }

        float nx[KNN], ny[KNN], nz[KNN];
        #pragma unroll
        for (int r = 0; r < KNN; ++r) {
            const int sel = (int)((k2[r] >> 16) & 0xffffULL); // orig idx payload
            nx[r] = batch[sel * 3 + 0];
            ny[r] = batch[sel * 3 + 1];
            nz[r] = batch[sel * 3 + 2];
        }
        float sx = nx[0], sy = ny[0], sz = nz[0];
        #pragma unroll
        for (int r = 1; r < KNN; ++r) {
            sx = __fadd_rn(sx, nx[r]);
            sy = __fadd_rn(sy, ny[r]);
            sz = __fadd_rn(sz, nz[r]);
        }
        const float cx = __fdiv_rn(sx, 5.0f);
        const float cy = __fdiv_rn(sy, 5.0f);
        const float cz = __fdiv_rn(sz, 5.0f);

        float sxx = 0.0f, syy = 0.0f, szz = 0.0f;
        #pragma unroll
        for (int r = 0; r < KNN; ++r) {
            const float dx = __fsub_rn(nx[r], cx);
            const float dy = __fsub_rn(ny[r], cy);
            const float dz = __fsub_rn(nz[r], cz);
            sxx = __fadd_rn(sxx, __fmul_rn(dx, dx));
            syy = __fadd_rn(syy, __fmul_rn(dy, dy));
            szz = __fadd_rn(szz, __fmul_rn(dz, dz));
        }
        const float trace = __fadd_rn(__fadd_rn(__fmul_rn(sxx, 0.25f),
                                                __fmul_rn(syy, 0.25f)),
                                      __fmul_rn(szz, 0.25f));
        trace_out[(size_t)b * N_PTS + bi[qs]] = trace;
    }
}

// ---------------- K3: r1-proven curvature normalize (in-place) ----------------
__global__ __launch_bounds__(256)
void curvature_kernel(float* __restrict__ io)
{
    __shared__ float red[256];
    const int b = blockIdx.x;
    const int t = threadIdx.x;
    float* __restrict__ tr = io + (size_t)b * N_PTS;

    float v[16];
    float s = 0.0f;
    #pragma unroll
    for (int i = 0; i < 16; ++i) {
        v[i] = tr[t + i * 256];
        s += v[i];
    }
    red[t] = s;
    __syncthreads();
    #pragma unroll
    for (int o = 128; o > 0; o >>= 1) {
        if (t < o) red[t] += red[t + o];
        __syncthreads();
    }
    const float denom = red[0] + 1e-8f;
    #pragma unroll
    for (int i = 0; i < 16; ++i)
        tr[t + i * 256] = v[i] / denom;
}

extern "C" void kernel_launch(void* const* d_in, const int* in_sizes, int n_in,
                              void* d_out, int out_size, void* d_ws, size_t ws_size,
                              hipStream_t stream)
{
    (void)in_sizes; (void)n_in; (void)out_size; (void)ws_size;
    const float* pcd = (const float*)d_in[0];   // [8,4096,3] f32
    float* out = (float*)d_out;                 // [8,4096] f32

    char* w = (char*)d_ws;
    float4* spts  = (float4*)w;                         // 512 KB
    u16*    sidxp = (u16*)(w + 524288);                 // 64 KB
    u32*    table = (u32*)(w + 524288 + 65536);         // 8*130*4 B

    build_kernel<<<BATCH, 256, 0, stream>>>(pcd, spts, sidxp, table);
    dim3 g2(N_PTS / (NTHR / 64 * QPW), BATCH);          // 64 x 8 = 512 blocks
    knn_kernel<<<g2, NTHR, 0, stream>>>(pcd, spts, sidxp, table, out);
    curvature_kernel<<<BATCH, 256, 0, stream>>>(out);
}